// Round 1
// baseline (2738.017 us; speedup 1.0000x reference)
//
#include <hip/hip_runtime.h>
#include <stdint.h>

// Problem constants (fixed by the reference).
#define NN 16384      // nodes
#define EE 524288     // edges
#define BB 32         // batch
#define DD 64         // input dim
#define OO 64         // output dim
#define FF 2048       // D*B features per node
#define MM 5          // num diffusion matrices

__device__ __forceinline__ float bf2f(unsigned short u) {
    return __uint_as_float(((unsigned int)u) << 16);
}
__device__ __forceinline__ unsigned short f2bf(float f) {
    unsigned int u = __float_as_uint(f);
    u += 0x7fffu + ((u >> 16) & 1u);   // round-to-nearest-even
    return (unsigned short)(u >> 16);
}
__device__ __forceinline__ unsigned int pack2(float a, float b) {
    return (unsigned int)f2bf(a) | ((unsigned int)f2bf(b) << 16);
}

// ---------------------------------------------------------------- histogram
__global__ __launch_bounds__(256) void hist_kernel(
    const float* __restrict__ adj, const int* __restrict__ rows,
    const int* __restrict__ cols,
    float* __restrict__ drow, float* __restrict__ dcol,
    int* __restrict__ cnt_row, int* __restrict__ cnt_col)
{
    int e = blockIdx.x * 256 + threadIdx.x;
    if (e < EE) {
        float a = adj[e];
        int r = rows[e], c = cols[e];
        atomicAdd(&drow[r], a);
        atomicAdd(&dcol[c], a);
        atomicAdd(&cnt_row[r], 1);
        atomicAdd(&cnt_col[c], 1);
    }
}

// ---------------------------------------------------------------- scan
// One block per array (grid=2), 1024 threads, 16 elements/thread.
__global__ __launch_bounds__(1024) void scan_kernel(
    const int* __restrict__ cnt_col, const int* __restrict__ cnt_row,
    int* __restrict__ off_col, int* __restrict__ off_row,
    int* __restrict__ cur_col, int* __restrict__ cur_row)
{
    const int* cnt = (blockIdx.x == 0) ? cnt_col : cnt_row;
    int* off = (blockIdx.x == 0) ? off_col : off_row;
    int* cur = (blockIdx.x == 0) ? cur_col : cur_row;

    __shared__ int part[1024];
    int t = threadIdx.x;
    int base = t * 16;
    int local[16];
    int s = 0;
#pragma unroll
    for (int i = 0; i < 16; i++) { local[i] = cnt[base + i]; s += local[i]; }
    part[t] = s;
    __syncthreads();
    // Hillis-Steele inclusive scan over 1024 partials
    for (int d = 1; d < 1024; d <<= 1) {
        int v = (t >= d) ? part[t - d] : 0;
        __syncthreads();
        part[t] += v;
        __syncthreads();
    }
    int run = (t == 0) ? 0 : part[t - 1];
#pragma unroll
    for (int i = 0; i < 16; i++) {
        off[base + i] = run;
        cur[base + i] = run;
        run += local[i];
    }
    if (t == 1023) off[NN] = run;
}

// ---------------------------------------------------------------- scatter
__global__ __launch_bounds__(256) void scatter_kernel(
    const float* __restrict__ adj, const int* __restrict__ rows,
    const int* __restrict__ cols,
    const float* __restrict__ drow, const float* __restrict__ dcol,
    int* __restrict__ cur_col, int* __restrict__ cur_row,
    int* __restrict__ src1, float* __restrict__ w1,
    int* __restrict__ src2, float* __restrict__ w2)
{
    int e = blockIdx.x * 256 + threadIdx.x;
    if (e < EE) {
        float a = adj[e];
        int r = rows[e], c = cols[e];
        float dr = drow[r];
        float idr = (dr > 0.f) ? (1.f / dr) : 0.f;
        float dc = dcol[c];
        float idc = (dc > 0.f) ? (1.f / dc) : 0.f;
        // support1: gather src=rows, scatter dst=cols -> CSR over cols
        int p1 = atomicAdd(&cur_col[c], 1);
        src1[p1] = r;
        w1[p1] = a * idr;
        // support2: gather src=cols, scatter dst=rows -> CSR over rows
        int p2 = atomicAdd(&cur_row[r], 1);
        src2[p2] = c;
        w2[p2] = a * idc;
    }
}

// ---------------------------------------------------------------- transpose
// inputs [B,N,D] fp32 -> x0 [N, D*B] bf16   (f = d*B + b)
__global__ __launch_bounds__(256) void transpose_kernel(
    const float* __restrict__ inp, unsigned short* __restrict__ x0)
{
    __shared__ float lds[DD * 33];   // stride 33 to break bank conflicts
    int n = blockIdx.x;
    int t = threadIdx.x;
#pragma unroll
    for (int i = 0; i < 8; i++) {
        int idx = t + i * 256;          // 0..2047
        int b = idx >> 6;               // 0..31
        int d = idx & 63;               // 0..63
        lds[d * 33 + b] = inp[(size_t)b * NN * DD + (size_t)n * DD + d];
    }
    __syncthreads();
    // f = t*8 + j ; d = f>>5 ; b = f&31. 8 consecutive f share d.
    int d = t >> 2;
    int b0 = (t & 3) * 8;
    const float* lp = &lds[d * 33 + b0];
    uint4 v;
    v.x = pack2(lp[0], lp[1]);
    v.y = pack2(lp[2], lp[3]);
    v.z = pack2(lp[4], lp[5]);
    v.w = pack2(lp[6], lp[7]);
    *(uint4*)(x0 + (size_t)n * FF + (size_t)t * 8) = v;
}

// ---------------------------------------------------------------- spmm
// xout[n,:] = alpha * sum_{e in CSR[n]} w[e]*xin[src[e],:]  (+ beta*z[n,:])
__global__ __launch_bounds__(256) void spmm_kernel(
    const unsigned short* __restrict__ xin,
    const unsigned short* __restrict__ z,
    unsigned short* __restrict__ xout,
    const int* __restrict__ off, const int* __restrict__ src,
    const float* __restrict__ w,
    float alpha, float beta, int has_z)
{
    int n = blockIdx.x;
    int t = threadIdx.x;
    int e0 = off[n], e1 = off[n + 1];
    size_t fo = (size_t)t * 8;

    float acc[8];
#pragma unroll
    for (int j = 0; j < 8; j++) acc[j] = 0.f;

    for (int e = e0; e < e1; ++e) {
        int s = src[e];
        float wv = w[e];
        uint4 v = *(const uint4*)(xin + (size_t)s * FF + fo);
        acc[0] = fmaf(wv, __uint_as_float(v.x << 16), acc[0]);
        acc[1] = fmaf(wv, __uint_as_float(v.x & 0xffff0000u), acc[1]);
        acc[2] = fmaf(wv, __uint_as_float(v.y << 16), acc[2]);
        acc[3] = fmaf(wv, __uint_as_float(v.y & 0xffff0000u), acc[3]);
        acc[4] = fmaf(wv, __uint_as_float(v.z << 16), acc[4]);
        acc[5] = fmaf(wv, __uint_as_float(v.z & 0xffff0000u), acc[5]);
        acc[6] = fmaf(wv, __uint_as_float(v.w << 16), acc[6]);
        acc[7] = fmaf(wv, __uint_as_float(v.w & 0xffff0000u), acc[7]);
    }

    if (has_z) {
        uint4 zv = *(const uint4*)(z + (size_t)n * FF + fo);
        float zf[8];
        zf[0] = __uint_as_float(zv.x << 16);
        zf[1] = __uint_as_float(zv.x & 0xffff0000u);
        zf[2] = __uint_as_float(zv.y << 16);
        zf[3] = __uint_as_float(zv.y & 0xffff0000u);
        zf[4] = __uint_as_float(zv.z << 16);
        zf[5] = __uint_as_float(zv.z & 0xffff0000u);
        zf[6] = __uint_as_float(zv.w << 16);
        zf[7] = __uint_as_float(zv.w & 0xffff0000u);
#pragma unroll
        for (int j = 0; j < 8; j++) acc[j] = alpha * acc[j] + beta * zf[j];
    }

    uint4 o;
    o.x = pack2(acc[0], acc[1]);
    o.y = pack2(acc[2], acc[3]);
    o.z = pack2(acc[4], acc[5]);
    o.w = pack2(acc[6], acc[7]);
    *(uint4*)(xout + (size_t)n * FF + fo) = o;
}

// ---------------------------------------------------------------- final GEMM
// out[b,n,o] = bias[o] + sum_{d,m} Xm[n, d*32+b] * W[d*5+m, o]
__global__ __launch_bounds__(256) void final_kernel(
    const unsigned short* __restrict__ X0, const unsigned short* __restrict__ X1,
    const unsigned short* __restrict__ X2, const unsigned short* __restrict__ X3,
    const unsigned short* __restrict__ X4,
    const float* __restrict__ Wt, const float* __restrict__ bias,
    float* __restrict__ out)
{
    __shared__ __align__(16) unsigned short xl[MM][FF];   // 20 KB
    int n = blockIdx.x;
    int t = threadIdx.x;
    const unsigned short* Xs[MM] = {X0, X1, X2, X3, X4};
    size_t fo = (size_t)t * 8;
#pragma unroll
    for (int m = 0; m < MM; m++) {
        *(uint4*)&xl[m][t * 8] = *(const uint4*)(Xs[m] + (size_t)n * FF + fo);
    }
    __syncthreads();

    int b = t >> 3;            // 0..31
    int o0 = (t & 7) * 8;      // 0,8,...,56

    float acc[8];
    float4 ba = *(const float4*)(bias + o0);
    float4 bb2 = *(const float4*)(bias + o0 + 4);
    acc[0] = ba.x; acc[1] = ba.y; acc[2] = ba.z; acc[3] = ba.w;
    acc[4] = bb2.x; acc[5] = bb2.y; acc[6] = bb2.z; acc[7] = bb2.w;

    for (int d = 0; d < DD; ++d) {
#pragma unroll
        for (int m = 0; m < MM; m++) {
            float x = bf2f(xl[m][d * BB + b]);
            const float* wr = Wt + (size_t)(d * MM + m) * OO + o0;
            float4 wa = *(const float4*)wr;
            float4 wb = *(const float4*)(wr + 4);
            acc[0] = fmaf(x, wa.x, acc[0]);
            acc[1] = fmaf(x, wa.y, acc[1]);
            acc[2] = fmaf(x, wa.z, acc[2]);
            acc[3] = fmaf(x, wa.w, acc[3]);
            acc[4] = fmaf(x, wb.x, acc[4]);
            acc[5] = fmaf(x, wb.y, acc[5]);
            acc[6] = fmaf(x, wb.z, acc[6]);
            acc[7] = fmaf(x, wb.w, acc[7]);
        }
    }

    float* op = out + ((size_t)b * NN + n) * OO + o0;
    *(float4*)op = make_float4(acc[0], acc[1], acc[2], acc[3]);
    *(float4*)(op + 4) = make_float4(acc[4], acc[5], acc[6], acc[7]);
}

// ---------------------------------------------------------------- launch
extern "C" void kernel_launch(void* const* d_in, const int* in_sizes, int n_in,
                              void* d_out, int out_size, void* d_ws, size_t ws_size,
                              hipStream_t stream)
{
    (void)in_sizes; (void)n_in; (void)out_size; (void)ws_size;
    const float* inputs  = (const float*)d_in[0];
    const float* adj     = (const float*)d_in[1];
    const int*   rows    = (const int*)d_in[2];
    const int*   cols    = (const int*)d_in[3];
    const float* weights = (const float*)d_in[4];
    const float* bias    = (const float*)d_in[5];
    float* out = (float*)d_out;

    char* ws = (char*)d_ws;
    size_t off = 0;
    auto alloc = [&](size_t bytes) -> char* {
        char* p = ws + off;
        off = (off + bytes + 255) & ~(size_t)255;
        return p;
    };
    float* drow    = (float*)alloc(NN * 4);
    float* dcol    = (float*)alloc(NN * 4);
    int* cnt_col   = (int*)alloc(NN * 4);
    int* cnt_row   = (int*)alloc(NN * 4);
    int* off_col   = (int*)alloc((NN + 1) * 4);
    int* off_row   = (int*)alloc((NN + 1) * 4);
    int* cur_col   = (int*)alloc(NN * 4);
    int* cur_row   = (int*)alloc(NN * 4);
    int* src1      = (int*)alloc((size_t)EE * 4);
    float* w1      = (float*)alloc((size_t)EE * 4);
    int* src2      = (int*)alloc((size_t)EE * 4);
    float* w2      = (float*)alloc((size_t)EE * 4);
    unsigned short* X[MM];
    for (int m = 0; m < MM; m++) X[m] = (unsigned short*)alloc((size_t)NN * FF * 2);

    // zero the atomic accumulators (drow,dcol,cnt_col,cnt_row are contiguous)
    hipMemsetAsync(drow, 0, (size_t)NN * 4 * 4, stream);

    hist_kernel<<<EE / 256, 256, 0, stream>>>(adj, rows, cols, drow, dcol,
                                              cnt_row, cnt_col);
    scan_kernel<<<2, 1024, 0, stream>>>(cnt_col, cnt_row, off_col, off_row,
                                        cur_col, cur_row);
    scatter_kernel<<<EE / 256, 256, 0, stream>>>(adj, rows, cols, drow, dcol,
                                                 cur_col, cur_row,
                                                 src1, w1, src2, w2);
    transpose_kernel<<<NN, 256, 0, stream>>>(inputs, X[0]);

    // xs1 = S1 x0
    spmm_kernel<<<NN, 256, 0, stream>>>(X[0], nullptr, X[1], off_col, src1, w1,
                                        1.f, 0.f, 0);
    // xs2 = 2*S1 xs1 - x0
    spmm_kernel<<<NN, 256, 0, stream>>>(X[1], X[0], X[2], off_col, src1, w1,
                                        2.f, -1.f, 1);
    // xs3 = S2 xs1   (x0 was NOT reset between supports)
    spmm_kernel<<<NN, 256, 0, stream>>>(X[1], nullptr, X[3], off_row, src2, w2,
                                        1.f, 0.f, 0);
    // xs4 = 2*S2 xs3 - xs1
    spmm_kernel<<<NN, 256, 0, stream>>>(X[3], X[1], X[4], off_row, src2, w2,
                                        2.f, -1.f, 1);

    final_kernel<<<NN, 256, 0, stream>>>(X[0], X[1], X[2], X[3], X[4],
                                         weights, bias, out);
}

// Round 2
// 1777.435 us; speedup vs baseline: 1.5404x; 1.5404x over previous
//
#include <hip/hip_runtime.h>
#include <stdint.h>

// Problem constants (fixed by the reference).
#define NN 16384      // nodes
#define EE 524288     // edges
#define BB 32         // batch
#define DD 64         // input dim
#define OO 64         // output dim
#define MM 5          // num diffusion matrices
#define KK 320        // D*M  (GEMM reduction dim)
#define KP 328        // padded LDS stride for A tile

typedef __attribute__((ext_vector_type(8))) short short8;
typedef __attribute__((ext_vector_type(4))) float floatx4;

__device__ __forceinline__ float bf2f(unsigned short u) {
    return __uint_as_float(((unsigned int)u) << 16);
}
__device__ __forceinline__ unsigned short f2bf(float f) {
    unsigned int u = __float_as_uint(f);
    u += 0x7fffu + ((u >> 16) & 1u);   // round-to-nearest-even
    return (unsigned short)(u >> 16);
}
__device__ __forceinline__ unsigned int pack2(float a, float b) {
    return (unsigned int)f2bf(a) | ((unsigned int)f2bf(b) << 16);
}

// ---------------------------------------------------------------- histogram
__global__ __launch_bounds__(256) void hist_kernel(
    const float* __restrict__ adj, const int* __restrict__ rows,
    const int* __restrict__ cols,
    float* __restrict__ drow, float* __restrict__ dcol,
    int* __restrict__ cnt_row, int* __restrict__ cnt_col)
{
    int e = blockIdx.x * 256 + threadIdx.x;
    if (e < EE) {
        float a = adj[e];
        int r = rows[e], c = cols[e];
        atomicAdd(&drow[r], a);
        atomicAdd(&dcol[c], a);
        atomicAdd(&cnt_row[r], 1);
        atomicAdd(&cnt_col[c], 1);
    }
}

// ---------------------------------------------------------------- scan
// One block per array (grid=2), 1024 threads, 16 elements/thread.
__global__ __launch_bounds__(1024) void scan_kernel(
    const int* __restrict__ cnt_col, const int* __restrict__ cnt_row,
    int* __restrict__ off_col, int* __restrict__ off_row,
    int* __restrict__ cur_col, int* __restrict__ cur_row)
{
    const int* cnt = (blockIdx.x == 0) ? cnt_col : cnt_row;
    int* off = (blockIdx.x == 0) ? off_col : off_row;
    int* cur = (blockIdx.x == 0) ? cur_col : cur_row;

    __shared__ int part[1024];
    int t = threadIdx.x;
    int base = t * 16;
    int local[16];
    int s = 0;
#pragma unroll
    for (int i = 0; i < 16; i++) { local[i] = cnt[base + i]; s += local[i]; }
    part[t] = s;
    __syncthreads();
    for (int d = 1; d < 1024; d <<= 1) {
        int v = (t >= d) ? part[t - d] : 0;
        __syncthreads();
        part[t] += v;
        __syncthreads();
    }
    int run = (t == 0) ? 0 : part[t - 1];
#pragma unroll
    for (int i = 0; i < 16; i++) {
        off[base + i] = run;
        cur[base + i] = run;
        run += local[i];
    }
    if (t == 1023) off[NN] = run;
}

// ---------------------------------------------------------------- scatter
__global__ __launch_bounds__(256) void scatter_kernel(
    const float* __restrict__ adj, const int* __restrict__ rows,
    const int* __restrict__ cols,
    const float* __restrict__ drow, const float* __restrict__ dcol,
    int* __restrict__ cur_col, int* __restrict__ cur_row,
    int* __restrict__ src1, float* __restrict__ w1,
    int* __restrict__ src2, float* __restrict__ w2)
{
    int e = blockIdx.x * 256 + threadIdx.x;
    if (e < EE) {
        float a = adj[e];
        int r = rows[e], c = cols[e];
        float dr = drow[r];
        float idr = (dr > 0.f) ? (1.f / dr) : 0.f;
        float dc = dcol[c];
        float idc = (dc > 0.f) ? (1.f / dc) : 0.f;
        int p1 = atomicAdd(&cur_col[c], 1);   // support1: dst=cols, src=rows
        src1[p1] = r;
        w1[p1] = a * idr;
        int p2 = atomicAdd(&cur_row[r], 1);   // support2: dst=rows, src=cols
        src2[p2] = c;
        w2[p2] = a * idc;
    }
}

// ---------------------------------------------------------------- cast
// inputs [B,N,D] fp32 -> x0 [B,N,D] bf16 (pure elementwise cast; the [B,N,D]
// layout makes final-GEMM A rows contiguous in d).
__global__ __launch_bounds__(256) void cast_kernel(
    const float* __restrict__ inp, unsigned short* __restrict__ x0)
{
    size_t i = ((size_t)blockIdx.x * 256 + threadIdx.x) * 8;
    float4 a = *(const float4*)(inp + i);
    float4 b = *(const float4*)(inp + i + 4);
    uint4 o;
    o.x = pack2(a.x, a.y);
    o.y = pack2(a.z, a.w);
    o.z = pack2(b.x, b.y);
    o.w = pack2(b.z, b.w);
    *(uint4*)(x0 + i) = o;
}

// ---------------------------------------------------------------- W prep
// Wt[o][k'] bf16 with k' = m*64 + d, i.e. Wt[o*320 + m*64 + d] = W[(d*5+m)*64 + o]
__global__ __launch_bounds__(256) void wprep_kernel(
    const float* __restrict__ W, unsigned short* __restrict__ Wt)
{
    int i = blockIdx.x * 256 + threadIdx.x;
    if (i < OO * KK) {
        int o = i / KK;
        int kp = i - o * KK;
        int m = kp >> 6;
        int d = kp & 63;
        Wt[i] = f2bf(W[(d * MM + m) * OO + o]);
    }
}

// ---------------------------------------------------------------- spmm
// layout [B,N,D]: xout[b,n,:] = alpha * sum_e w[e]*xin[b,src[e],:] (+beta*z[b,n,:])
// block = node n; thread t -> (b = t>>3, d-group = t&7)
__global__ __launch_bounds__(256) void spmm_kernel(
    const unsigned short* __restrict__ xin,
    const unsigned short* __restrict__ z,
    unsigned short* __restrict__ xout,
    const int* __restrict__ off, const int* __restrict__ src,
    const float* __restrict__ w,
    float alpha, float beta, int has_z)
{
    int n = blockIdx.x;
    int t = threadIdx.x;
    int b = t >> 3;
    int dg = (t & 7) * 8;
    int e0 = off[n], e1 = off[n + 1];
    size_t bstride = (size_t)b * NN;

    float acc[8];
#pragma unroll
    for (int j = 0; j < 8; j++) acc[j] = 0.f;

    for (int e = e0; e < e1; ++e) {
        int s = src[e];
        float wv = w[e];
        uint4 v = *(const uint4*)(xin + (bstride + s) * DD + dg);
        acc[0] = fmaf(wv, __uint_as_float(v.x << 16), acc[0]);
        acc[1] = fmaf(wv, __uint_as_float(v.x & 0xffff0000u), acc[1]);
        acc[2] = fmaf(wv, __uint_as_float(v.y << 16), acc[2]);
        acc[3] = fmaf(wv, __uint_as_float(v.y & 0xffff0000u), acc[3]);
        acc[4] = fmaf(wv, __uint_as_float(v.z << 16), acc[4]);
        acc[5] = fmaf(wv, __uint_as_float(v.z & 0xffff0000u), acc[5]);
        acc[6] = fmaf(wv, __uint_as_float(v.w << 16), acc[6]);
        acc[7] = fmaf(wv, __uint_as_float(v.w & 0xffff0000u), acc[7]);
    }

    size_t fo = (bstride + n) * DD + dg;
    if (has_z) {
        uint4 zv = *(const uint4*)(z + fo);
        float zf[8];
        zf[0] = __uint_as_float(zv.x << 16);
        zf[1] = __uint_as_float(zv.x & 0xffff0000u);
        zf[2] = __uint_as_float(zv.y << 16);
        zf[3] = __uint_as_float(zv.y & 0xffff0000u);
        zf[4] = __uint_as_float(zv.z << 16);
        zf[5] = __uint_as_float(zv.z & 0xffff0000u);
        zf[6] = __uint_as_float(zv.w << 16);
        zf[7] = __uint_as_float(zv.w & 0xffff0000u);
#pragma unroll
        for (int j = 0; j < 8; j++) acc[j] = alpha * acc[j] + beta * zf[j];
    }

    uint4 o;
    o.x = pack2(acc[0], acc[1]);
    o.y = pack2(acc[2], acc[3]);
    o.z = pack2(acc[4], acc[5]);
    o.w = pack2(acc[6], acc[7]);
    *(uint4*)(xout + fo) = o;
}

// ---------------------------------------------------------------- final GEMM (MFMA)
// C[r = b*N+n, o] = bias[o] + sum_{k'} A[r,k'] * Wp[k',o],  k' = m*64+d
// A[r, m*64+d] = Xm[b][n][d]   (contiguous in d under the [B,N,D] layout)
// Block: 64 rows (one b, 64 consecutive n) x 64 cols. 4 waves, one 16-row
// strip each. A staged in LDS (stride KP=328: even bank distribution).
// B-frags read straight from global Wt[64][320] bf16 (40 KB, L1/L2-resident;
// each wave touches W exactly once per block).
__global__ __launch_bounds__(256) void final_mfma(
    const unsigned short* __restrict__ X0, const unsigned short* __restrict__ X1,
    const unsigned short* __restrict__ X2, const unsigned short* __restrict__ X3,
    const unsigned short* __restrict__ X4,
    const unsigned short* __restrict__ Wt, const float* __restrict__ bias,
    float* __restrict__ out)
{
    __shared__ __align__(16) unsigned short A_lds[64 * KP];   // 41984 B -> 3 blocks/CU
    int blk = blockIdx.x;
    int b = blk >> 8;              // 256 node-tiles per batch element
    int n0 = (blk & 255) * 64;
    int t = threadIdx.x;
    const unsigned short* Xs[MM] = {X0, X1, X2, X3, X4};

    // Stage A tile: 5 matrices x 64 rows x 64 d = 2560 uint4 loads, coalesced.
#pragma unroll
    for (int i = 0; i < 10; i++) {
        int idx = t + i * 256;             // 0..2559
        int dgv = (idx & 7) * 8;           // d0
        int row = (idx >> 3) & 63;
        int m = idx >> 9;                  // 0..4
        uint4 v = *(const uint4*)(Xs[m] + ((size_t)b * NN + n0 + row) * DD + dgv);
        *(uint4*)&A_lds[row * KP + m * 64 + dgv] = v;
    }
    __syncthreads();

    int wave = t >> 6;
    int lane = t & 63;
    int col = lane & 15;
    int quad = lane >> 4;

    floatx4 acc[4];
#pragma unroll
    for (int ct = 0; ct < 4; ct++) acc[ct] = (floatx4){0.f, 0.f, 0.f, 0.f};

    const unsigned short* abase = &A_lds[(wave * 16 + col) * KP + quad * 8];
#pragma unroll
    for (int kt = 0; kt < 10; kt++) {
        short8 a = *(const short8*)(abase + kt * 32);
#pragma unroll
        for (int ct = 0; ct < 4; ct++) {
            short8 bf = *(const short8*)(Wt + (size_t)(ct * 16 + col) * KK + kt * 32 + quad * 8);
            acc[ct] = __builtin_amdgcn_mfma_f32_16x16x32_bf16(a, bf, acc[ct], 0, 0, 0);
        }
    }

    // C/D layout: col = lane&15, row = quad*4 + reg
    size_t rbase = (size_t)b * NN + n0 + wave * 16 + quad * 4;
#pragma unroll
    for (int ct = 0; ct < 4; ct++) {
        int o = ct * 16 + col;
        float bv = bias[o];
#pragma unroll
        for (int r = 0; r < 4; r++) {
            out[(rbase + r) * OO + o] = acc[ct][r] + bv;
        }
    }
}

// ---------------------------------------------------------------- launch
extern "C" void kernel_launch(void* const* d_in, const int* in_sizes, int n_in,
                              void* d_out, int out_size, void* d_ws, size_t ws_size,
                              hipStream_t stream)
{
    (void)in_sizes; (void)n_in; (void)out_size; (void)ws_size;
    const float* inputs  = (const float*)d_in[0];
    const float* adj     = (const float*)d_in[1];
    const int*   rows    = (const int*)d_in[2];
    const int*   cols    = (const int*)d_in[3];
    const float* weights = (const float*)d_in[4];
    const float* bias    = (const float*)d_in[5];
    float* out = (float*)d_out;

    char* ws = (char*)d_ws;
    size_t off = 0;
    auto alloc = [&](size_t bytes) -> char* {
        char* p = ws + off;
        off = (off + bytes + 255) & ~(size_t)255;
        return p;
    };
    float* drow    = (float*)alloc(NN * 4);
    float* dcol    = (float*)alloc(NN * 4);
    int* cnt_col   = (int*)alloc(NN * 4);
    int* cnt_row   = (int*)alloc(NN * 4);
    int* off_col   = (int*)alloc((NN + 1) * 4);
    int* off_row   = (int*)alloc((NN + 1) * 4);
    int* cur_col   = (int*)alloc(NN * 4);
    int* cur_row   = (int*)alloc(NN * 4);
    int* src1      = (int*)alloc((size_t)EE * 4);
    float* w1      = (float*)alloc((size_t)EE * 4);
    int* src2      = (int*)alloc((size_t)EE * 4);
    float* w2      = (float*)alloc((size_t)EE * 4);
    unsigned short* Wt = (unsigned short*)alloc((size_t)OO * KK * 2);
    unsigned short* X[MM];
    for (int m = 0; m < MM; m++) X[m] = (unsigned short*)alloc((size_t)NN * BB * DD * 2);

    // zero the atomic accumulators (drow,dcol,cnt_col,cnt_row are contiguous)
    hipMemsetAsync(drow, 0, (size_t)NN * 4 * 4, stream);

    hist_kernel<<<EE / 256, 256, 0, stream>>>(adj, rows, cols, drow, dcol,
                                              cnt_row, cnt_col);
    scan_kernel<<<2, 1024, 0, stream>>>(cnt_col, cnt_row, off_col, off_row,
                                        cur_col, cur_row);
    scatter_kernel<<<EE / 256, 256, 0, stream>>>(adj, rows, cols, drow, dcol,
                                                 cur_col, cur_row,
                                                 src1, w1, src2, w2);
    cast_kernel<<<(BB * NN * DD) / (256 * 8), 256, 0, stream>>>(inputs, X[0]);
    wprep_kernel<<<(OO * KK + 255) / 256, 256, 0, stream>>>(weights, Wt);

    // xs1 = S1 x0
    spmm_kernel<<<NN, 256, 0, stream>>>(X[0], nullptr, X[1], off_col, src1, w1,
                                        1.f, 0.f, 0);
    // xs2 = 2*S1 xs1 - x0
    spmm_kernel<<<NN, 256, 0, stream>>>(X[1], X[0], X[2], off_col, src1, w1,
                                        2.f, -1.f, 1);
    // xs3 = S2 xs1   (x0 deliberately NOT reset between supports)
    spmm_kernel<<<NN, 256, 0, stream>>>(X[1], nullptr, X[3], off_row, src2, w2,
                                        1.f, 0.f, 0);
    // xs4 = 2*S2 xs3 - xs1
    spmm_kernel<<<NN, 256, 0, stream>>>(X[3], X[1], X[4], off_row, src2, w2,
                                        2.f, -1.f, 1);

    final_mfma<<<BB * (NN / 64), 256, 0, stream>>>(X[0], X[1], X[2], X[3], X[4],
                                                   Wt, bias, out);
}

// Round 3
// 1491.242 us; speedup vs baseline: 1.8361x; 1.1919x over previous
//
#include <hip/hip_runtime.h>
#include <stdint.h>

// Problem constants (fixed by the reference).
#define NN 16384      // nodes
#define EE 524288     // edges
#define BB 32         // batch
#define DD 64         // input dim
#define OO 64         // output dim
#define MM 5          // num diffusion matrices
#define KK 320        // D*M  (GEMM reduction dim)
#define KP 328        // padded LDS stride for A tile

typedef __attribute__((ext_vector_type(8))) short short8;
typedef __attribute__((ext_vector_type(4))) float floatx4;

__device__ __forceinline__ float bf2f(unsigned short u) {
    return __uint_as_float(((unsigned int)u) << 16);
}
__device__ __forceinline__ unsigned short f2bf(float f) {
    unsigned int u = __float_as_uint(f);
    u += 0x7fffu + ((u >> 16) & 1u);   // round-to-nearest-even
    return (unsigned short)(u >> 16);
}
__device__ __forceinline__ unsigned int pack2(float a, float b) {
    return (unsigned int)f2bf(a) | ((unsigned int)f2bf(b) << 16);
}

// ---------------------------------------------------------------- histogram
__global__ __launch_bounds__(256) void hist_kernel(
    const float* __restrict__ adj, const int* __restrict__ rows,
    const int* __restrict__ cols,
    float* __restrict__ drow, float* __restrict__ dcol,
    int* __restrict__ cnt_row, int* __restrict__ cnt_col)
{
    int e = blockIdx.x * 256 + threadIdx.x;
    if (e < EE) {
        float a = adj[e];
        int r = rows[e], c = cols[e];
        atomicAdd(&drow[r], a);
        atomicAdd(&dcol[c], a);
        atomicAdd(&cnt_row[r], 1);
        atomicAdd(&cnt_col[c], 1);
    }
}

// ---------------------------------------------------------------- scan
// One block per array (grid=2), 1024 threads, 16 elements/thread.
__global__ __launch_bounds__(1024) void scan_kernel(
    const int* __restrict__ cnt_col, const int* __restrict__ cnt_row,
    int* __restrict__ off_col, int* __restrict__ off_row,
    int* __restrict__ cur_col, int* __restrict__ cur_row)
{
    const int* cnt = (blockIdx.x == 0) ? cnt_col : cnt_row;
    int* off = (blockIdx.x == 0) ? off_col : off_row;
    int* cur = (blockIdx.x == 0) ? cur_col : cur_row;

    __shared__ int part[1024];
    int t = threadIdx.x;
    int base = t * 16;
    int local[16];
    int s = 0;
#pragma unroll
    for (int i = 0; i < 16; i++) { local[i] = cnt[base + i]; s += local[i]; }
    part[t] = s;
    __syncthreads();
    for (int d = 1; d < 1024; d <<= 1) {
        int v = (t >= d) ? part[t - d] : 0;
        __syncthreads();
        part[t] += v;
        __syncthreads();
    }
    int run = (t == 0) ? 0 : part[t - 1];
#pragma unroll
    for (int i = 0; i < 16; i++) {
        off[base + i] = run;
        cur[base + i] = run;
        run += local[i];
    }
    if (t == 1023) off[NN] = run;
}

// ---------------------------------------------------------------- scatter
// Builds packed CSR edge arrays: edge[e] = {src, w_as_bits}
__global__ __launch_bounds__(256) void scatter_kernel(
    const float* __restrict__ adj, const int* __restrict__ rows,
    const int* __restrict__ cols,
    const float* __restrict__ drow, const float* __restrict__ dcol,
    int* __restrict__ cur_col, int* __restrict__ cur_row,
    int2* __restrict__ edge1, int2* __restrict__ edge2)
{
    int e = blockIdx.x * 256 + threadIdx.x;
    if (e < EE) {
        float a = adj[e];
        int r = rows[e], c = cols[e];
        float dr = drow[r];
        float idr = (dr > 0.f) ? (1.f / dr) : 0.f;
        float dc = dcol[c];
        float idc = (dc > 0.f) ? (1.f / dc) : 0.f;
        int p1 = atomicAdd(&cur_col[c], 1);   // support1: dst=cols, src=rows
        edge1[p1] = make_int2(r, __float_as_int(a * idr));
        int p2 = atomicAdd(&cur_row[r], 1);   // support2: dst=rows, src=cols
        edge2[p2] = make_int2(c, __float_as_int(a * idc));
    }
}

// ---------------------------------------------------------------- cast
// inputs [B,N,D] fp32 -> x0 [B,N,D] bf16
__global__ __launch_bounds__(256) void cast_kernel(
    const float* __restrict__ inp, unsigned short* __restrict__ x0)
{
    size_t i = ((size_t)blockIdx.x * 256 + threadIdx.x) * 8;
    float4 a = *(const float4*)(inp + i);
    float4 b = *(const float4*)(inp + i + 4);
    uint4 o;
    o.x = pack2(a.x, a.y);
    o.y = pack2(a.z, a.w);
    o.z = pack2(b.x, b.y);
    o.w = pack2(b.z, b.w);
    *(uint4*)(x0 + i) = o;
}

// ---------------------------------------------------------------- W prep
// Wt[o][k'] bf16 with k' = m*64 + d
__global__ __launch_bounds__(256) void wprep_kernel(
    const float* __restrict__ W, unsigned short* __restrict__ Wt)
{
    int i = blockIdx.x * 256 + threadIdx.x;
    if (i < OO * KK) {
        int o = i / KK;
        int kp = i - o * KK;
        int m = kp >> 6;
        int d = kp & 63;
        Wt[i] = f2bf(W[(d * MM + m) * OO + o]);
    }
}

// ---------------------------------------------------------------- spmm
// One block = 32 dst nodes x ONE batch slice b. Thread t: node = n0+(t>>3),
// d-group = (t&7)*8 (one uint4 = 128B segment per edge per 8-lane group).
// XCD swizzle: blkid&7 selects XCD (dispatch round-robin heuristic); b = bhi*8
// + xcd so all concurrent blocks on an XCD share one 2 MB X b-slice -> the
// ~32x in-degree reuse of X rows is captured in that XCD's 4 MB L2.
__global__ __launch_bounds__(256) void spmm_kernel(
    const unsigned short* __restrict__ xin,
    const unsigned short* __restrict__ z,
    unsigned short* __restrict__ xout,
    const int* __restrict__ off, const int2* __restrict__ edges,
    float alpha, float beta, int has_z)
{
    unsigned int l = blockIdx.x;          // 0..16383
    int xcd  = l & 7;
    unsigned int s = l >> 3;              // 0..2047
    int bhi  = s >> 9;                    // 0..3
    int ntile = s & 511;                  // 0..511
    int b = bhi * 8 + xcd;

    int t = threadIdx.x;
    int n = ntile * 32 + (t >> 3);
    int dg = (t & 7) * 8;
    int e0 = off[n], e1 = off[n + 1];
    const unsigned short* xb = xin + (size_t)b * NN * DD;

    float acc[8];
#pragma unroll
    for (int j = 0; j < 8; j++) acc[j] = 0.f;

    for (int e = e0; e < e1; ++e) {
        int2 ed = edges[e];
        float wv = __int_as_float(ed.y);
        uint4 v = *(const uint4*)(xb + (size_t)ed.x * DD + dg);
        acc[0] = fmaf(wv, __uint_as_float(v.x << 16), acc[0]);
        acc[1] = fmaf(wv, __uint_as_float(v.x & 0xffff0000u), acc[1]);
        acc[2] = fmaf(wv, __uint_as_float(v.y << 16), acc[2]);
        acc[3] = fmaf(wv, __uint_as_float(v.y & 0xffff0000u), acc[3]);
        acc[4] = fmaf(wv, __uint_as_float(v.z << 16), acc[4]);
        acc[5] = fmaf(wv, __uint_as_float(v.z & 0xffff0000u), acc[5]);
        acc[6] = fmaf(wv, __uint_as_float(v.w << 16), acc[6]);
        acc[7] = fmaf(wv, __uint_as_float(v.w & 0xffff0000u), acc[7]);
    }

    size_t fo = ((size_t)b * NN + n) * DD + dg;
    if (has_z) {
        uint4 zv = *(const uint4*)(z + fo);
        float zf[8];
        zf[0] = __uint_as_float(zv.x << 16);
        zf[1] = __uint_as_float(zv.x & 0xffff0000u);
        zf[2] = __uint_as_float(zv.y << 16);
        zf[3] = __uint_as_float(zv.y & 0xffff0000u);
        zf[4] = __uint_as_float(zv.z << 16);
        zf[5] = __uint_as_float(zv.z & 0xffff0000u);
        zf[6] = __uint_as_float(zv.w << 16);
        zf[7] = __uint_as_float(zv.w & 0xffff0000u);
#pragma unroll
        for (int j = 0; j < 8; j++) acc[j] = alpha * acc[j] + beta * zf[j];
    }

    uint4 o;
    o.x = pack2(acc[0], acc[1]);
    o.y = pack2(acc[2], acc[3]);
    o.z = pack2(acc[4], acc[5]);
    o.w = pack2(acc[6], acc[7]);
    *(uint4*)(xout + fo) = o;
}

// ---------------------------------------------------------------- final GEMM (MFMA)
__global__ __launch_bounds__(256) void final_mfma(
    const unsigned short* __restrict__ X0, const unsigned short* __restrict__ X1,
    const unsigned short* __restrict__ X2, const unsigned short* __restrict__ X3,
    const unsigned short* __restrict__ X4,
    const unsigned short* __restrict__ Wt, const float* __restrict__ bias,
    float* __restrict__ out)
{
    __shared__ __align__(16) unsigned short A_lds[64 * KP];   // 41984 B
    int blk = blockIdx.x;
    int b = blk >> 8;
    int n0 = (blk & 255) * 64;
    int t = threadIdx.x;
    const unsigned short* Xs[MM] = {X0, X1, X2, X3, X4};

#pragma unroll
    for (int i = 0; i < 10; i++) {
        int idx = t + i * 256;             // 0..2559
        int dgv = (idx & 7) * 8;
        int row = (idx >> 3) & 63;
        int m = idx >> 9;
        uint4 v = *(const uint4*)(Xs[m] + ((size_t)b * NN + n0 + row) * DD + dgv);
        *(uint4*)&A_lds[row * KP + m * 64 + dgv] = v;
    }
    __syncthreads();

    int wave = t >> 6;
    int lane = t & 63;
    int col = lane & 15;
    int quad = lane >> 4;

    floatx4 acc[4];
#pragma unroll
    for (int ct = 0; ct < 4; ct++) acc[ct] = (floatx4){0.f, 0.f, 0.f, 0.f};

    const unsigned short* abase = &A_lds[(wave * 16 + col) * KP + quad * 8];
#pragma unroll
    for (int kt = 0; kt < 10; kt++) {
        short8 a = *(const short8*)(abase + kt * 32);
#pragma unroll
        for (int ct = 0; ct < 4; ct++) {
            short8 bf = *(const short8*)(Wt + (size_t)(ct * 16 + col) * KK + kt * 32 + quad * 8);
            acc[ct] = __builtin_amdgcn_mfma_f32_16x16x32_bf16(a, bf, acc[ct], 0, 0, 0);
        }
    }

    size_t rbase = (size_t)b * NN + n0 + wave * 16 + quad * 4;
#pragma unroll
    for (int ct = 0; ct < 4; ct++) {
        int o = ct * 16 + col;
        float bv = bias[o];
#pragma unroll
        for (int r = 0; r < 4; r++) {
            out[(rbase + r) * OO + o] = acc[ct][r] + bv;
        }
    }
}

// ---------------------------------------------------------------- launch
extern "C" void kernel_launch(void* const* d_in, const int* in_sizes, int n_in,
                              void* d_out, int out_size, void* d_ws, size_t ws_size,
                              hipStream_t stream)
{
    (void)in_sizes; (void)n_in; (void)out_size; (void)ws_size;
    const float* inputs  = (const float*)d_in[0];
    const float* adj     = (const float*)d_in[1];
    const int*   rows    = (const int*)d_in[2];
    const int*   cols    = (const int*)d_in[3];
    const float* weights = (const float*)d_in[4];
    const float* bias    = (const float*)d_in[5];
    float* out = (float*)d_out;

    char* ws = (char*)d_ws;
    size_t off = 0;
    auto alloc = [&](size_t bytes) -> char* {
        char* p = ws + off;
        off = (off + bytes + 255) & ~(size_t)255;
        return p;
    };
    float* drow    = (float*)alloc(NN * 4);
    float* dcol    = (float*)alloc(NN * 4);
    int* cnt_col   = (int*)alloc(NN * 4);
    int* cnt_row   = (int*)alloc(NN * 4);
    int* off_col   = (int*)alloc((NN + 1) * 4);
    int* off_row   = (int*)alloc((NN + 1) * 4);
    int* cur_col   = (int*)alloc(NN * 4);
    int* cur_row   = (int*)alloc(NN * 4);
    int2* edge1    = (int2*)alloc((size_t)EE * 8);
    int2* edge2    = (int2*)alloc((size_t)EE * 8);
    unsigned short* Wt = (unsigned short*)alloc((size_t)OO * KK * 2);
    unsigned short* X[MM];
    for (int m = 0; m < MM; m++) X[m] = (unsigned short*)alloc((size_t)NN * BB * DD * 2);

    // zero the atomic accumulators (drow,dcol,cnt_col,cnt_row are contiguous)
    hipMemsetAsync(drow, 0, (size_t)NN * 4 * 4, stream);

    hist_kernel<<<EE / 256, 256, 0, stream>>>(adj, rows, cols, drow, dcol,
                                              cnt_row, cnt_col);
    scan_kernel<<<2, 1024, 0, stream>>>(cnt_col, cnt_row, off_col, off_row,
                                        cur_col, cur_row);
    scatter_kernel<<<EE / 256, 256, 0, stream>>>(adj, rows, cols, drow, dcol,
                                                 cur_col, cur_row, edge1, edge2);
    cast_kernel<<<(BB * NN * DD) / (256 * 8), 256, 0, stream>>>(inputs, X[0]);
    wprep_kernel<<<(OO * KK + 255) / 256, 256, 0, stream>>>(weights, Wt);

    const int SPMM_GRID = 512 * BB;   // 512 node-tiles x 32 b, XCD-swizzled

    // xs1 = S1 x0
    spmm_kernel<<<SPMM_GRID, 256, 0, stream>>>(X[0], nullptr, X[1], off_col,
                                               edge1, 1.f, 0.f, 0);
    // xs2 = 2*S1 xs1 - x0
    spmm_kernel<<<SPMM_GRID, 256, 0, stream>>>(X[1], X[0], X[2], off_col,
                                               edge1, 2.f, -1.f, 1);
    // xs3 = S2 xs1   (x0 deliberately NOT reset between supports)
    spmm_kernel<<<SPMM_GRID, 256, 0, stream>>>(X[1], nullptr, X[3], off_row,
                                               edge2, 1.f, 0.f, 0);
    // xs4 = 2*S2 xs3 - xs1
    spmm_kernel<<<SPMM_GRID, 256, 0, stream>>>(X[3], X[1], X[4], off_row,
                                               edge2, 2.f, -1.f, 1);

    final_mfma<<<BB * (NN / 64), 256, 0, stream>>>(X[0], X[1], X[2], X[3], X[4],
                                                   Wt, bias, out);
}